// Round 7
// baseline (415.911 us; speedup 1.0000x reference)
//
#include <hip/hip_runtime.h>
#include <math.h>
#include <stdint.h>

// R7: (a) k4 main loop reverted to R5's proven 2-barrier single-buffer
// schedule (R6 A/B: 1-barrier dbuf was ~35us slower); fused epilogue kept.
// (b) k3 occupancy 1->4 blocks/CU: 1024 blocks, waves split m-loop, LDS
// combine. (c) k1 inner loop float4-vectorized (b128 LDS broadcasts).
constexpr int B_ = 16, N_ = 2048, C_ = 256, K_ = 64;
constexpr float EPS_BN = 1e-5f;

typedef __attribute__((ext_vector_type(8))) short short8;
typedef __attribute__((ext_vector_type(16))) float f32x16;

#define MFMA32(A, Bf, Cc) __builtin_amdgcn_mfma_f32_32x32x16_bf16(A, Bf, Cc, 0, 0, 0)

// ---- workspace byte offsets ----
constexpr size_t SZ_QK  = (size_t)B_*N_*K_*2;            // 4 MiB each
constexpr size_t WSB_QH = 0;
constexpr size_t WSB_QL = WSB_QH + SZ_QK;
constexpr size_t WSB_KH = WSB_QL + SZ_QK;
constexpr size_t WSB_KL = WSB_KH + SZ_QK;
constexpr size_t WSB_Z  = WSB_KL + SZ_QK;                // B*N f32
constexpr size_t WSB_S  = WSB_Z  + (size_t)B_*N_*4;      // C f32 bn scale
constexpr size_t WSB_CB = WSB_S  + (size_t)C_*4;         // C f32 bn bias
constexpr size_t WSB_WBH= WSB_CB + (size_t)C_*4;         // C*C bf16 Wt hi [o][c]
constexpr size_t WSB_WBL= WSB_WBH+ (size_t)C_*C_*2;      // C*C bf16 Wt lo
constexpr size_t WSB_XT = (WSB_WBL + (size_t)C_*C_*2 + 255) & ~(size_t)255;
constexpr size_t XT_HALF= (size_t)B_*N_*C_*2;            // 16.78 MB (hi), lo at +XT_HALF

__device__ inline unsigned short bf16_rne(float f) {
  uint32_t u = __float_as_uint(f);
  uint32_t r = u + 0x7FFFu + ((u >> 16) & 1u);
  return (unsigned short)(r >> 16);
}

#define GLOAD_LDS16(g, l) __builtin_amdgcn_global_load_lds( \
    (const __attribute__((address_space(1))) unsigned int*)(g), \
    (__attribute__((address_space(3))) unsigned int*)(l), 16, 0, 0)

// ---------------------------------------------------------------------------
// K0: split Wt to bf16 hi/lo [o][c], fold BN affine
__global__ void k0_prep(const float* __restrict__ Wt, const float* __restrict__ bt,
                        const float* __restrict__ gamma, const float* __restrict__ beta,
                        const float* __restrict__ mean, const float* __restrict__ var,
                        char* __restrict__ ws) {
  int o = blockIdx.x, c = threadIdx.x;
  {
    float w = Wt[(size_t)o*C_ + c];
    uint32_t wb = __float_as_uint(w) & 0xFFFF0000u;
    ((unsigned short*)(ws + WSB_WBH))[(size_t)o*C_ + c] = (unsigned short)(wb >> 16);
    ((unsigned short*)(ws + WSB_WBL))[(size_t)o*C_ + c] = bf16_rne(w - __uint_as_float(wb));
  }
  if (o == 0) {
    float s = gamma[c] * rsqrtf(var[c] + EPS_BN);
    ((float*)(ws + WSB_S))[c]  = s;
    ((float*)(ws + WSB_CB))[c] = s * (bt[c] - mean[c]) + beta[c];
  }
}

// ---------------------------------------------------------------------------
// K1: q/k projections -> split bf16 [b][n][64]; x -> split bf16 xT tiles in
// ws (layout [b][nt][nchunk 4][c 256][8 n] 16B words) for k4 global_load_lds.
// Inner GEMM vectorized: float4 over c (ds_read_b128 broadcasts, VALU-bound).
__global__ __launch_bounds__(256) void k1_qk(const float* __restrict__ x,
                                             const float* __restrict__ Wq,
                                             const float* __restrict__ Wk,
                                             char* __restrict__ ws,
                                             char* __restrict__ xtbuf) {
  __shared__ float xs[32][260];
  unsigned short* qh = (unsigned short*)(ws + WSB_QH);
  unsigned short* ql = (unsigned short*)(ws + WSB_QL);
  unsigned short* kh = (unsigned short*)(ws + WSB_KH);
  unsigned short* kl = (unsigned short*)(ws + WSB_KL);
  int b = blockIdx.x >> 6, nt = blockIdx.x & 63;
  int n0 = nt * 32, tid = threadIdx.x;

  const float4* xg = (const float4*)(x + ((size_t)b*N_ + n0)*C_);
#pragma unroll
  for (int i = 0; i < 8; i++) {
    int f = tid + i*256;
    int r = f >> 6, c4 = f & 63;
    *(float4*)&xs[r][c4*4] = xg[f];
  }
  __syncthreads();

  int o = tid & 63, rg = tid >> 6;   // rg uniform per wave -> xs reads broadcast
  float aq[8], ak[8];
#pragma unroll
  for (int j = 0; j < 8; j++) { aq[j] = 0.f; ak[j] = 0.f; }
  const float4* wqr = (const float4*)(Wq + (size_t)o*C_);  // row-major float4
  const float4* wkr = (const float4*)(Wk + (size_t)o*C_);
  for (int c4 = 0; c4 < 64; c4++) {
    float4 wq4 = wqr[c4];
    float4 wk4 = wkr[c4];
    float4 xv[8];
#pragma unroll
    for (int j = 0; j < 8; j++) xv[j] = *(const float4*)&xs[rg*8 + j][c4*4];
#pragma unroll
    for (int j = 0; j < 8; j++) {
      aq[j] = fmaf(xv[j].x, wq4.x, aq[j]); ak[j] = fmaf(xv[j].x, wk4.x, ak[j]);
      aq[j] = fmaf(xv[j].y, wq4.y, aq[j]); ak[j] = fmaf(xv[j].y, wk4.y, ak[j]);
      aq[j] = fmaf(xv[j].z, wq4.z, aq[j]); ak[j] = fmaf(xv[j].z, wk4.z, ak[j]);
      aq[j] = fmaf(xv[j].w, wq4.w, aq[j]); ak[j] = fmaf(xv[j].w, wk4.w, ak[j]);
    }
  }
#pragma unroll
  for (int j = 0; j < 8; j++) {
    int n = n0 + rg*8 + j;
    size_t base = ((size_t)b*N_ + n)*K_ + o;
    float q = aq[j];
    uint32_t qb = __float_as_uint(q) & 0xFFFF0000u;
    qh[base] = (unsigned short)(qb >> 16);
    ql[base] = bf16_rne(q - __uint_as_float(qb));
    float k = ak[j];
    uint32_t kb = __float_as_uint(k) & 0xFFFF0000u;
    kh[base] = (unsigned short)(kb >> 16);
    kl[base] = bf16_rne(k - __uint_as_float(kb));
  }
#pragma unroll
  for (int nc = 0; nc < 4; nc++) {
    uint32_t hw[4], lw[4];
#pragma unroll
    for (int jj = 0; jj < 4; jj++) {
      float a  = xs[nc*8 + jj*2    ][tid];
      float bv = xs[nc*8 + jj*2 + 1][tid];
      uint32_t ab = __float_as_uint(a)  & 0xFFFF0000u;
      uint32_t bb = __float_as_uint(bv) & 0xFFFF0000u;
      hw[jj] = (ab >> 16) | bb;
      float alo = a  - __uint_as_float(ab);
      float blo = bv - __uint_as_float(bb);
      lw[jj] = (uint32_t)bf16_rne(alo) | ((uint32_t)bf16_rne(blo) << 16);
    }
    size_t toff = ((size_t)(b*64 + nt))*16384 + ((size_t)nc*256 + tid)*16;
    *(uint4*)(xtbuf + toff)           = make_uint4(hw[0], hw[1], hw[2], hw[3]);
    *(uint4*)(xtbuf + XT_HALF + toff) = make_uint4(lw[0], lw[1], lw[2], lw[3]);
  }
}

// ---------------------------------------------------------------------------
// K3: Z[n] = rowmax_m(e) + ln(rowsum exp). Block = 32 n; 4 waves split the
// 64 m-tiles 16 each; LDS combine. Grid B*64 = 1024 blocks (4/CU).
__global__ __launch_bounds__(256) void k3_stats(char* __restrict__ ws) {
  __shared__ float redM[4][32], redS[4][32];
  int b = blockIdx.x >> 6, nb = blockIdx.x & 63;
  int tid = threadIdx.x, wave = tid >> 6, l = tid & 63;
  int lo5 = l & 31, hi5 = l >> 5;
  int n = nb*32 + lo5;

  short8 qhf[4], qlf[4];
  size_t qoff = ((size_t)b*N_ + n)*K_;
#pragma unroll
  for (int cs = 0; cs < 4; cs++) {
    qhf[cs] = *(const short8*)(ws + WSB_QH + (qoff + cs*16 + hi5*8)*2);
    qlf[cs] = *(const short8*)(ws + WSB_QL + (qoff + cs*16 + hi5*8)*2);
  }
  float M = -3.0e38f, S = 0.f;
  for (int mt = wave*16; mt < wave*16 + 16; mt++) {
    size_t koff = ((size_t)b*N_ + mt*32 + lo5)*K_;
    short8 khf[4], klf[4];
#pragma unroll
    for (int cs = 0; cs < 4; cs++) {
      khf[cs] = *(const short8*)(ws + WSB_KH + (koff + cs*16 + hi5*8)*2);
      klf[cs] = *(const short8*)(ws + WSB_KL + (koff + cs*16 + hi5*8)*2);
    }
    f32x16 E = {0.f};
#pragma unroll
    for (int cs = 0; cs < 4; cs++) {
      E = MFMA32(khf[cs], qhf[cs], E);
      E = MFMA32(khf[cs], qlf[cs], E);
      E = MFMA32(klf[cs], qhf[cs], E);
    }
    float tmax = E[0];
#pragma unroll
    for (int r = 1; r < 16; r++) tmax = fmaxf(tmax, E[r]);
    float nM = fmaxf(M, tmax);
    float sc = __expf(M - nM);
    float ss = 0.f;
#pragma unroll
    for (int r = 0; r < 16; r++) ss += __expf(E[r] - nM);
    S = fmaf(S, sc, ss);
    M = nM;
  }
  float Mo = __shfl_xor(M, 32, 64);
  float So = __shfl_xor(S, 32, 64);
  float Mg = fmaxf(M, Mo);
  float Sg = S*__expf(M - Mg) + So*__expf(Mo - Mg);
  if (hi5 == 0) { redM[wave][lo5] = Mg; redS[wave][lo5] = Sg; }
  __syncthreads();
  if (tid < 32) {
    float M0 = redM[0][tid], M1 = redM[1][tid], M2 = redM[2][tid], M3 = redM[3][tid];
    float Mt = fmaxf(fmaxf(M0, M1), fmaxf(M2, M3));
    float St = redS[0][tid]*__expf(M0 - Mt) + redS[1][tid]*__expf(M1 - Mt)
             + redS[2][tid]*__expf(M2 - Mt) + redS[3][tid]*__expf(M3 - Mt);
    ((float*)(ws + WSB_Z))[(size_t)b*N_ + nb*32 + tid] = Mt + __logf(St);
  }
}

// ---------------------------------------------------------------------------
// K4: O[m,c] = sum_n P[n,m]*x[n,c] (R5 schedule: stage; barrier; compute;
// barrier), then fused epilogue: d = x - O*ics -> split bf16 -> swizzled LDS
// -> MFMA vs WtBF -> BN+ReLU+residual -> out.
__global__ __launch_bounds__(256) void k4_ov(const float* __restrict__ x,
                                             char* __restrict__ ws,
                                             float* __restrict__ out) {
  __shared__ __align__(16) char xtile[65536];   // main loop: 32KB; epi: 64KB
  __shared__ float zs[32];
  __shared__ float csL[64];
  int b = blockIdx.x >> 5, mblk = blockIdx.x & 31;
  int m0 = mblk*64;
  int tid = threadIdx.x, wave = tid >> 6, l = tid & 63;
  int lo5 = l & 31, hi5 = l >> 5;
  int msub = wave >> 1, c0 = (wave & 1)*128;
  int mg = m0 + msub*32 + lo5;
  const float* Zp = (const float*)(ws + WSB_Z);
  const char* XTH = ws + WSB_XT;
  const char* XTL = ws + WSB_XT + XT_HALF;

  short8 khf[4], klf[4];                      // loop-invariant B-frags (cols m)
  size_t koff = ((size_t)b*N_ + mg)*K_;
#pragma unroll
  for (int cs = 0; cs < 4; cs++) {
    khf[cs] = *(const short8*)(ws + WSB_KH + (koff + cs*16 + hi5*8)*2);
    klf[cs] = *(const short8*)(ws + WSB_KL + (koff + cs*16 + hi5*8)*2);
  }
  f32x16 accO[4];
#pragma unroll
  for (int ct = 0; ct < 4; ct++) accO[ct] = (f32x16){0.f};
  float csum = 0.f;

  for (int nt = 0; nt < 64; nt++) {
    __syncthreads();   // prior tile's reads done before overwrite
    size_t src = (size_t)(b*64 + nt)*16384 + (size_t)tid*16;
#pragma unroll
    for (int i = 0; i < 4; i++) GLOAD_LDS16(XTH + src + (size_t)i*4096, xtile + tid*16 + i*4096);
#pragma unroll
    for (int i = 0; i < 4; i++) GLOAD_LDS16(XTL + src + (size_t)i*4096, xtile + 16384 + tid*16 + i*4096);
    if (tid < 32) zs[tid] = Zp[(size_t)b*N_ + nt*32 + tid];
    short8 qh8[4], ql8[4];
    size_t qoff2 = ((size_t)b*N_ + nt*32 + lo5)*K_;
#pragma unroll
    for (int cs = 0; cs < 4; cs++) {
      qh8[cs] = *(const short8*)(ws + WSB_QH + (qoff2 + cs*16 + hi5*8)*2);
      ql8[cs] = *(const short8*)(ws + WSB_QL + (qoff2 + cs*16 + hi5*8)*2);
    }
    __syncthreads();
    f32x16 E = {0.f};
#pragma unroll
    for (int cs = 0; cs < 4; cs++) {
      E = MFMA32(qh8[cs], khf[cs], E);
      E = MFMA32(qh8[cs], klf[cs], E);
      E = MFMA32(ql8[cs], khf[cs], E);
    }
    float ph[16], pl[16];
#pragma unroll
    for (int r = 0; r < 16; r++) {
      int nr = (r & 3) + 8*(r >> 2) + 4*hi5;
      float p = __expf(E[r] - zs[nr]);
      csum += p;
      uint32_t pb = __float_as_uint(p) & 0xFFFF0000u;
      ph[r] = __uint_as_float(pb);
      pl[r] = p - ph[r];
    }
    uint32_t Wh[8], Wl[8];
#pragma unroll
    for (int i = 0; i < 8; i++) {
      Wh[i] = (__float_as_uint(ph[2*i]) >> 16) | (__float_as_uint(ph[2*i+1]) & 0xFFFF0000u);
      uint32_t w;
      asm("v_cvt_pk_bf16_f32 %0, %1, %2" : "=v"(w) : "v"(pl[2*i]), "v"(pl[2*i+1]));
      Wl[i] = w;
    }
    short8 pha[2], pla[2];
#pragma unroll
    for (int s = 0; s < 2; s++) {
      uint32_t a0 = Wh[s*4+0], b0 = Wh[s*4+2];
      uint32_t a1 = Wh[s*4+1], b1 = Wh[s*4+3];
      asm("v_permlane32_swap_b32 %0, %1" : "+v"(a0), "+v"(b0));
      asm("v_permlane32_swap_b32 %0, %1" : "+v"(a1), "+v"(b1));
      union { uint32_t w[4]; short8 s8; } uh;
      uh.w[0] = a0; uh.w[1] = a1; uh.w[2] = b0; uh.w[3] = b1;
      pha[s] = uh.s8;
      uint32_t c0w = Wl[s*4+0], d0 = Wl[s*4+2];
      uint32_t c1w = Wl[s*4+1], d1 = Wl[s*4+3];
      asm("v_permlane32_swap_b32 %0, %1" : "+v"(c0w), "+v"(d0));
      asm("v_permlane32_swap_b32 %0, %1" : "+v"(c1w), "+v"(d1));
      union { uint32_t w[4]; short8 s8; } ul;
      ul.w[0] = c0w; ul.w[1] = c1w; ul.w[2] = d0; ul.w[3] = d1;
      pla[s] = ul.s8;
    }
#pragma unroll
    for (int ct = 0; ct < 4; ct++) {
      int cc = c0 + ct*32 + lo5;
      short8 bh[2], bl[2];
#pragma unroll
      for (int ns = 0; ns < 2; ns++) {
        size_t off = ((size_t)((ns*2 + hi5)*256 + cc))*16;
        bh[ns] = *(const short8*)(xtile + off);
        bl[ns] = *(const short8*)(xtile + 16384 + off);
      }
#pragma unroll
      for (int ns = 0; ns < 2; ns++) {
        accO[ct] = MFMA32(pha[ns], bh[ns], accO[ct]);
        accO[ct] = MFMA32(pha[ns], bl[ns], accO[ct]);
        accO[ct] = MFMA32(pla[ns], bh[ns], accO[ct]);
      }
    }
  }

  // ---- fused epilogue: d-split -> swizzled LDS -> MFMA vs WtBF -> out
  csum += __shfl_xor(csum, 32, 64);
  if ((wave & 1) == 0 && hi5 == 0) csL[msub*32 + lo5] = csum;
  __syncthreads();
#pragma unroll
  for (int r = 0; r < 16; r++) {
    int mloc = msub*32 + (r & 3) + 8*(r >> 2) + 4*hi5;
    float ics = 1.0f / (1e-6f + csL[mloc]);
#pragma unroll
    for (int ct = 0; ct < 4; ct++) {
      int cc = c0 + ct*32 + lo5;
      float xv = x[((size_t)b*N_ + m0 + mloc)*C_ + cc];
      float dv = fmaf(-accO[ct][r], ics, xv);
      uint32_t db = __float_as_uint(dv) & 0xFFFF0000u;
      int byte = mloc*512 + ((((cc >> 3) ^ (mloc & 31)) << 4)) + ((cc & 7) << 1);
      *(unsigned short*)(xtile + byte)         = (unsigned short)(db >> 16);
      *(unsigned short*)(xtile + 32768 + byte) = bf16_rne(dv - __uint_as_float(db));
    }
  }
  __syncthreads();
  f32x16 accT[2][2];
#pragma unroll
  for (int ms = 0; ms < 2; ms++)
#pragma unroll
    for (int ot = 0; ot < 2; ot++) accT[ms][ot] = (f32x16){0.f};
#pragma unroll
  for (int cs = 0; cs < 16; cs++) {
    short8 ah[2], al[2], bh[2], bl[2];
#pragma unroll
    for (int ms = 0; ms < 2; ms++) {
      int off = (ms*32 + lo5)*512 + ((((cs*2 + hi5) ^ lo5)) << 4);
      ah[ms] = *(const short8*)(xtile + off);
      al[ms] = *(const short8*)(xtile + 32768 + off);
    }
#pragma unroll
    for (int ot = 0; ot < 2; ot++) {
      size_t wo = ((size_t)((wave*2 + ot)*32 + lo5)*C_ + cs*16 + hi5*8)*2;
      bh[ot] = *(const short8*)(ws + WSB_WBH + wo);
      bl[ot] = *(const short8*)(ws + WSB_WBL + wo);
    }
#pragma unroll
    for (int ms = 0; ms < 2; ms++)
#pragma unroll
      for (int ot = 0; ot < 2; ot++) {
        accT[ms][ot] = MFMA32(ah[ms], bh[ot], accT[ms][ot]);
        accT[ms][ot] = MFMA32(ah[ms], bl[ot], accT[ms][ot]);
        accT[ms][ot] = MFMA32(al[ms], bh[ot], accT[ms][ot]);
      }
  }
  const float* Sp = (const float*)(ws + WSB_S);
  const float* Cp = (const float*)(ws + WSB_CB);
  float sv[2], cv[2];
#pragma unroll
  for (int ot = 0; ot < 2; ot++) {
    int o = (wave*2 + ot)*32 + lo5;
    sv[ot] = Sp[o]; cv[ot] = Cp[o];
  }
#pragma unroll
  for (int ms = 0; ms < 2; ms++)
#pragma unroll
    for (int ot = 0; ot < 2; ot++)
#pragma unroll
      for (int r = 0; r < 16; r++) {
        int mloc = ms*32 + (r & 3) + 8*(r >> 2) + 4*hi5;
        int o = (wave*2 + ot)*32 + lo5;
        float bn = fmaf(sv[ot], accT[ms][ot][r], cv[ot]);
        bn = bn > 0.f ? bn : 0.f;
        size_t idx = ((size_t)b*N_ + m0 + mloc)*C_ + o;
        out[idx] = x[idx] + bn;
      }
}

// ---------------------------------------------------------------------------
extern "C" void kernel_launch(void* const* d_in, const int* in_sizes, int n_in,
                              void* d_out, int out_size, void* d_ws, size_t ws_size,
                              hipStream_t stream) {
  (void)in_sizes; (void)n_in; (void)out_size; (void)ws_size;
  const float* x     = (const float*)d_in[0];
  const float* Wq    = (const float*)d_in[1];
  const float* Wk    = (const float*)d_in[2];
  // d_in[3] (Wv) / d_in[4] (bv): dead in reference forward.
  const float* Wt    = (const float*)d_in[5];
  const float* bt    = (const float*)d_in[6];
  const float* gamma = (const float*)d_in[7];
  const float* beta  = (const float*)d_in[8];
  const float* mean  = (const float*)d_in[9];
  const float* var   = (const float*)d_in[10];
  char* ws = (char*)d_ws;
  float* out = (float*)d_out;

  k0_prep <<<C_,     C_,  0, stream>>>(Wt, bt, gamma, beta, mean, var, ws);
  k1_qk   <<<B_*64,  256, 0, stream>>>(x, Wq, Wk, ws, ws + WSB_XT);
  k3_stats<<<B_*64,  256, 0, stream>>>(ws);
  k4_ov   <<<B_*32,  256, 0, stream>>>(x, ws, out);
}